// Round 7
// baseline (1155.232 us; speedup 1.0000x reference)
//
#include <hip/hip_runtime.h>
#include <math.h>

#define NB 8192
#define IND 512
#define QDIM 128
#define CD 1024
#define KE 8
#define PD 64
#define ORB 32  // rows per k_output block

typedef _Float16 h8 __attribute__((ext_vector_type(8)));
typedef _Float16 h4 __attribute__((ext_vector_type(4)));
typedef float fx16 __attribute__((ext_vector_type(16)));

#define GLD16(g, l) __builtin_amdgcn_global_load_lds((const __attribute__((address_space(1))) void*)(g), (__attribute__((address_space(3))) void*)(l), 16, 0, 0)

__device__ __forceinline__ float softt(float v, float th) {
    float a = fabsf(v) - th;
    return a > 0.0f ? copysignf(a, v) : 0.0f;
}

// ---------------- split helpers: v = hi + lo * 2^-11 (lo stored pre-scaled by 2048)
__device__ __forceinline__ void fsplit(float v, _Float16& hi, _Float16& lo) {
    hi = (_Float16)v;
    lo = (_Float16)((v - (float)hi) * 2048.0f);
}

// ---------------- K0: M = Wq @ keys^T / sqrt(QDIM), sb = bq @ keys^T / sqrt(QDIM)
__global__ void k_precompute_M(const float* __restrict__ Wq, const float* __restrict__ keys,
                               const float* __restrict__ bq, float* __restrict__ M,
                               float* __restrict__ sb) {
    const float RSQ = 0.088388347648318447f; // 1/sqrt(128)
    int g = blockIdx.x * 256 + threadIdx.x;  // 0..4095
    if (g < IND * KE) {
        int i = g >> 3, k = g & 7;
        float s = 0.f;
        for (int q = 0; q < QDIM; ++q) s += Wq[i * QDIM + q] * keys[k * QDIM + q];
        M[g] = s * RSQ;  // M[i*8+k]
    }
    if (blockIdx.x == 0 && threadIdx.x < KE) {
        int k = threadIdx.x;
        float s = 0.f;
        for (int q = 0; q < QDIM; ++q) s += bq[q] * keys[k * QDIM + q];
        sb[k] = s * RSQ;
    }
}

// ---------------- K1: per-row scores -> expert idx (one wave per row, no atomics)
__global__ __launch_bounds__(256)
void k_scores(const float* __restrict__ x, const float* __restrict__ M,
              const float* __restrict__ sb, int* __restrict__ idx) {
    __shared__ float Ms[KE][IND];
    __shared__ float sbs[KE];
    int t = threadIdx.x;
    #pragma unroll
    for (int j = 0; j < 16; ++j) {
        int e = j * 256 + t;
        Ms[e & 7][e >> 3] = M[e];
    }
    if (t < KE) sbs[t] = sb[t];
    __syncthreads();
    int w = t >> 6, lane = t & 63;
    int row = blockIdx.x * 4 + w;
    const float* xr = x + (size_t)row * IND;
    float sc[KE];
    #pragma unroll
    for (int k = 0; k < KE; ++k) sc[k] = 0.f;
    #pragma unroll
    for (int j = 0; j < IND / 64; ++j) {
        int ii = lane + 64 * j;
        float xv = xr[ii];
        #pragma unroll
        for (int k = 0; k < KE; ++k) sc[k] += xv * Ms[k][ii];
    }
    #pragma unroll
    for (int k = 0; k < KE; ++k) {
        #pragma unroll
        for (int off = 32; off >= 1; off >>= 1) sc[k] += __shfl_down(sc[k], off, 64);
    }
    if (lane == 0) {
        float smax = -1e30f;
        #pragma unroll
        for (int k = 0; k < KE; ++k) { sc[k] += sbs[k]; smax = fmaxf(smax, sc[k]); }
        const float LN09 = -0.105360515657826301f;  // ln(0.9)
        int e = 0;
        #pragma unroll
        for (int k = KE - 1; k >= 0; --k)
            if (sc[k] >= smax + LN09) e = k;  // smallest eligible k (sl is increasing)
        idx[row] = e;
    }
}

// ---------------- K2: single-block counting sort: counts, offsets, perm (no global atomics)
__global__ __launch_bounds__(256)
void k_count(const int* __restrict__ idx, int* __restrict__ perm,
             int* __restrict__ counts, int* __restrict__ offsets) {
    __shared__ int hist[256][KE];      // 8 KB
    __shared__ int sc[2][KE][256];     // 16 KB ping-pong scan
    __shared__ int base[KE];
    const int t = threadIdx.x;
    int pc[KE];
    #pragma unroll
    for (int e = 0; e < KE; ++e) pc[e] = 0;
    // strided (coalesced) row assignment: thread t owns rows {t, 256+t, ...}
    for (int j = 0; j < NB / 256; ++j) pc[idx[j * 256 + t]]++;
    #pragma unroll
    for (int e = 0; e < KE; ++e) { hist[t][e] = pc[e]; sc[0][e][t] = pc[e]; }
    __syncthreads();
    int cur = 0;
    for (int d = 1; d < 256; d <<= 1) {
        #pragma unroll
        for (int e = 0; e < KE; ++e) {
            int v = sc[cur][e][t];
            if (t >= d) v += sc[cur][e][t - d];
            sc[cur ^ 1][e][t] = v;
        }
        cur ^= 1;
        __syncthreads();
    }
    if (t == 0) {
        int a = 0;
        #pragma unroll
        for (int e = 0; e < KE; ++e) {
            int tot = sc[cur][e][255];
            base[e] = a; offsets[e] = a; counts[e] = tot; a += tot;
        }
    }
    __syncthreads();
    int pos[KE];
    #pragma unroll
    for (int e = 0; e < KE; ++e) pos[e] = base[e] + sc[cur][e][t] - hist[t][e];
    for (int j = 0; j < NB / 256; ++j) {
        int r = j * 256 + t;
        int e = idx[r];
        perm[pos[e]++] = r;
    }
}

// ---------------- K4: elementwise split of x into hi/lo fp16 planes
__global__ __launch_bounds__(256)
void k_split_rows(const float* __restrict__ src, _Float16* __restrict__ ph,
                  _Float16* __restrict__ pl, int n) {
    int i = (blockIdx.x * 256 + threadIdx.x) * 4;
    if (i < n) {
        float4 v = *(const float4*)(src + i);
        h4 hh, ll;
        #pragma unroll
        for (int j = 0; j < 4; ++j) {
            _Float16 a, b;
            fsplit((&v.x)[j], a, b);
            hh[j] = a; ll[j] = b;
        }
        *(h4*)(ph + i) = hh;
        *(h4*)(pl + i) = ll;
    }
}

// ---------------- K5: transpose+split: src[e][K][CD] fp32 -> th/tl[e][CD][K] fp16
__global__ __launch_bounds__(256)
void k_tsplit(const float* __restrict__ src, _Float16* __restrict__ th,
              _Float16* __restrict__ tl, int K) {
    __shared__ float tile[64][65];
    int e = blockIdx.z;
    int k0 = blockIdx.x * 64;
    int n0 = blockIdx.y * 64;
    const float* s = src + (size_t)e * K * CD;
    int t = threadIdx.x;
    int tr = t >> 4;
    int tc = (t & 15) * 4;
    #pragma unroll
    for (int p = 0; p < 4; ++p) {
        int kk = tr + p * 16;
        float4 v = *(const float4*)&s[(size_t)(k0 + kk) * CD + n0 + tc];
        #pragma unroll
        for (int j = 0; j < 4; ++j) tile[kk][tc + j] = (&v.x)[j];
    }
    __syncthreads();
    int n = t >> 2;
    int kq = (t & 3) * 16;
    h8 hh0, hh1, ll0, ll1;
    #pragma unroll
    for (int j = 0; j < 8; ++j) {
        _Float16 a, b;
        fsplit(tile[kq + j][n], a, b);
        hh0[j] = a; ll0[j] = b;
        fsplit(tile[kq + 8 + j][n], a, b);
        hh1[j] = a; ll1[j] = b;
    }
    size_t ob = ((size_t)e * CD + n0 + n) * K + k0 + kq;
    *(h8*)(th + ob) = hh0;
    *(h8*)(th + ob + 8) = hh1;
    *(h8*)(tl + ob) = ll0;
    *(h8*)(tl + ob + 8) = ll1;
}

// ---------------- grouped split-fp16 MFMA GEMM, 128x128 tile, BK=16 k-values,
// double-buffered async staging (2x16KB LDS -> 3 blocks/CU) + XCD swizzle.
// A planes: [row][KDIM] fp16 hi/lo (lo pre-scaled 2048). B planes: [e][CD][KDIM] K-major.
// LDS buffer: 128 rows x 4 chunks of 16B; chunk for (row, l) = row*4 + (l ^ ((row>>1)&3)),
// l = kg*2+comp — spreads frag ds_read_b128 over all 32 banks (row stride = 16 banks).
// acc1 = hi*hi; acc2 = hi*lo' + lo'*hi; result = acc1 + acc2*2^-11 (rel err 2^-22).
// MODE 0: Bx = gather(x)@We; write Bx fp32 + z hi/lo
// MODE 1: v += Bx; write z hi/lo
// MODE 2: v += Bx; write z fp32
template <int KDIM, int MODE>
__global__ __launch_bounds__(256, 3)
void k_mfma(const _Float16* __restrict__ Ah, const _Float16* __restrict__ Al,
            const _Float16* __restrict__ Bh, const _Float16* __restrict__ Bl,
            const float* __restrict__ theta, const float* __restrict__ BxBuf,
            float* __restrict__ BxOut, _Float16* __restrict__ zh, _Float16* __restrict__ zl,
            float* __restrict__ zf,
            const int* __restrict__ perm, const int* __restrict__ counts,
            const int* __restrict__ offsets) {
    const int e = blockIdx.z;
    const int cnt = counts[e];
    // XCD swizzle: consecutive p round-robin XCDs; give each XCD an 8x8 (x,y) sub-grid.
    const int p = blockIdx.x + 8 * blockIdx.y;
    const int gx = p & 7;
    const int qq = p >> 3;
    const int bxl = qq & 7;
    const int byl = gx + 8 * (qq >> 3);
    const int m0 = byl * 128;
    if (m0 >= cnt) return;
    const int n0 = bxl * 128;
    const int off = offsets[e];
    const float th = theta[e];

    __shared__ _Float16 Asl[2][4096];  // 8 KB per buffer
    __shared__ _Float16 Bsl[2][4096];

    const int t = threadIdx.x;
    const int lane = t & 63;
    const int w = t >> 6;

    // staging: 2 A + 2 B global_load_lds per thread per BK=16 step
    const _Float16* aptr[2];
    const _Float16* bptr[2];
    #pragma unroll
    for (int i = 0; i < 2; ++i) {
        int c = (w * 2 + i) * 64 + lane;     // chunk index 0..511
        int r = c >> 2;                       // row 0..127
        int s = c & 3;                        // physical chunk slot
        int l = s ^ ((r >> 1) & 3);           // logical: kg*2+comp
        int comp = l & 1;
        int kg = l >> 1;
        int mrow = m0 + r; if (mrow > cnt - 1) mrow = cnt - 1;
        size_t grow;
        if constexpr (MODE == 0) grow = (size_t)perm[off + mrow];
        else grow = (size_t)(off + mrow);
        aptr[i] = (comp ? Al : Ah) + grow * KDIM + kg * 8;
        bptr[i] = (comp ? Bl : Bh) + ((size_t)e * CD + n0 + r) * KDIM + kg * 8;
    }

    const int wm = w >> 1, wn = w & 1;
    const int q = lane >> 5;
    const int ml = lane & 31;

    fx16 acc1[2][2], acc2[2][2];
    #pragma unroll
    for (int mt = 0; mt < 2; ++mt)
        #pragma unroll
        for (int nt = 0; nt < 2; ++nt)
            #pragma unroll
            for (int g = 0; g < 16; ++g) { acc1[mt][nt][g] = 0.f; acc2[mt][nt][g] = 0.f; }

    auto stage = [&](int kt, int buf) {
        const int koff = kt * 16;
        #pragma unroll
        for (int i = 0; i < 2; ++i) {
            GLD16(aptr[i] + koff, &Asl[buf][(w * 2 + i) * 512]);
            GLD16(bptr[i] + koff, &Bsl[buf][(w * 2 + i) * 512]);
        }
    };

    const int NT = KDIM / 16;
    stage(0, 0);
    __syncthreads();
    for (int kt = 0; kt < NT; ++kt) {
        const int buf = kt & 1;
        if (kt + 1 < NT) stage(kt + 1, buf ^ 1);  // prefetch in flight during compute
        h8 ah[2], al2[2], bh2[2], bl2[2];
        #pragma unroll
        for (int mt = 0; mt < 2; ++mt) {
            int row = wm * 64 + mt * 32 + ml;
            int sw = (row >> 1) & 3;
            int l0 = q * 2;
            ah[mt]  = *(const h8*)&Asl[buf][(row * 4 + (l0 ^ sw)) * 8];
            al2[mt] = *(const h8*)&Asl[buf][(row * 4 + ((l0 + 1) ^ sw)) * 8];
        }
        #pragma unroll
        for (int nt = 0; nt < 2; ++nt) {
            int col = wn * 64 + nt * 32 + ml;
            int sw = (col >> 1) & 3;
            int l0 = q * 2;
            bh2[nt] = *(const h8*)&Bsl[buf][(col * 4 + (l0 ^ sw)) * 8];
            bl2[nt] = *(const h8*)&Bsl[buf][(col * 4 + ((l0 + 1) ^ sw)) * 8];
        }
        #pragma unroll
        for (int mt = 0; mt < 2; ++mt)
            #pragma unroll
            for (int nt = 0; nt < 2; ++nt) {
                acc1[mt][nt] = __builtin_amdgcn_mfma_f32_32x32x16_f16(ah[mt],  bh2[nt], acc1[mt][nt], 0, 0, 0);
                acc2[mt][nt] = __builtin_amdgcn_mfma_f32_32x32x16_f16(ah[mt],  bl2[nt], acc2[mt][nt], 0, 0, 0);
                acc2[mt][nt] = __builtin_amdgcn_mfma_f32_32x32x16_f16(al2[mt], bh2[nt], acc2[mt][nt], 0, 0, 0);
            }
        __syncthreads();  // drains prefetch after compute + protects buf reuse
    }

    // epilogue: C/D layout col=lane&31, row=(g&3)+8*(g>>2)+4*q  [m74/m101]
    const float LSC = 4.8828125e-4f;  // 2^-11
    #pragma unroll
    for (int mt = 0; mt < 2; ++mt)
        #pragma unroll
        for (int nt = 0; nt < 2; ++nt) {
            #pragma unroll
            for (int g = 0; g < 16; ++g) {
                int rl = wm * 64 + mt * 32 + (g & 3) + 8 * (g >> 2) + 4 * q;
                int mrow = m0 + rl;
                if (mrow < cnt) {
                    int col = n0 + wn * 64 + nt * 32 + ml;
                    size_t addr = (size_t)(off + mrow) * CD + col;
                    float v = acc1[mt][nt][g] + acc2[mt][nt][g] * LSC;
                    if constexpr (MODE == 0) {
                        BxOut[addr] = v;
                        float z = softt(v, th);
                        _Float16 a, b;
                        fsplit(z, a, b);
                        zh[addr] = a; zl[addr] = b;
                    } else if constexpr (MODE == 1) {
                        float z = softt(v + BxBuf[addr], th);
                        _Float16 a, b;
                        fsplit(z, a, b);
                        zh[addr] = a; zl[addr] = b;
                    } else {
                        zf[addr] = softt(v + BxBuf[addr], th);
                    }
                }
            }
        }
}

// ---------------- K6: per-row top-k threshold (bit search), emit compact (val,idx) lists
__global__ __launch_bounds__(256)
void k_prune(const float* __restrict__ z, const int* __restrict__ offsets,
             float* __restrict__ cval, int* __restrict__ cidx, int* __restrict__ rcnt) {
    __shared__ int red[4];
    __shared__ int wcnt;
    const int SL[KE] = {5, 150, 296, 441, 587, 732, 878, 1024};
    int slot = blockIdx.x;
    int k = 0;
    #pragma unroll
    for (int e = 1; e < KE; ++e)
        if (slot >= offsets[e]) k = e;
    int lvl = SL[k];
    int t = threadIdx.x;
    if (t == 0) wcnt = 0;
    const float* zr = z + (size_t)slot * CD;
    float v[4];
    unsigned ab[4];
    #pragma unroll
    for (int j = 0; j < 4; ++j) {
        v[j] = zr[t + 256 * j];
        ab[j] = __float_as_uint(fabsf(v[j]));
    }
    unsigned thr = 0;
    for (int b = 30; b >= 0; --b) {
        unsigned cand = thr | (1u << b);
        int c = 0;
        #pragma unroll
        for (int j = 0; j < 4; ++j) c += (ab[j] >= cand) ? 1 : 0;
        #pragma unroll
        for (int off = 32; off >= 1; off >>= 1) c += __shfl_down(c, off, 64);
        if ((t & 63) == 0) red[t >> 6] = c;
        __syncthreads();
        int tot = red[0] + red[1] + red[2] + red[3];
        if (tot >= lvl) thr = cand;
        __syncthreads();
    }
    float* cvr = cval + (size_t)slot * CD;
    int* cir = cidx + (size_t)slot * CD;
    #pragma unroll
    for (int j = 0; j < 4; ++j) {
        if (ab[j] >= thr) {
            int p = atomicAdd(&wcnt, 1);
            cvr[p] = v[j];
            cir[p] = t + 256 * j;
        }
    }
    __syncthreads();
    if (t == 0) rcnt[slot] = wcnt;
}

// ---------------- K7: out = relu(h) @ W2 + b2, h = b1 + sparse_z @ W1 (compact lists)
__global__ __launch_bounds__(256)
void k_output(const float* __restrict__ cval, const int* __restrict__ cidx,
              const int* __restrict__ rcnt,
              const float* __restrict__ W1, const float* __restrict__ b1,
              const float* __restrict__ W2, const float* __restrict__ b2,
              const int* __restrict__ perm, float* __restrict__ out) {
    __shared__ float W2s[64][68];
    __shared__ float hTs[64][34];
    __shared__ float cvS[ORB][16];
    __shared__ int   ciS[ORB][16];
    __shared__ int   cnS[ORB];

    const int t = threadIdx.x;
    const int s0 = blockIdx.x * ORB;

    if (t < ORB) cnS[t] = rcnt[s0 + t];
    __syncthreads();
    #pragma unroll
    for (int u = t; u < ORB * 16; u += 256) {
        int r = u >> 4, e = u & 15;
        int cnt = cnS[r];
        cvS[r][e] = (e < cnt) ? cval[(size_t)(s0 + r) * CD + e] : 0.f;
        ciS[r][e] = (e < cnt) ? cidx[(size_t)(s0 + r) * CD + e] : 0;
    }

    const int tm = t >> 4;
    const int tn = t & 15;
    const int iL = t & 63;
    const int rs = t >> 6;

    float acc0[4], acc1[4];
    #pragma unroll
    for (int j = 0; j < 4; ++j) { acc0[j] = 0.f; acc1[j] = 0.f; }

    for (int ch = 0; ch < 16; ++ch) {
        const int i0 = ch * 64;
        __syncthreads();
        #pragma unroll
        for (int p = 0; p < 4; ++p) {
            int kr = (t >> 4) + 16 * p;
            float4 w = *(const float4*)&W2[(size_t)(i0 + kr) * PD + (t & 15) * 4];
            *(float4*)&W2s[kr][(t & 15) * 4] = w;
        }
        float bv = b1[i0 + iL];
        #pragma unroll
        for (int jj = 0; jj < 8; ++jj) {
            int r = rs * 8 + jj;
            int cnt = cnS[r];
            float acc = bv;
            float wv[16];
            #pragma unroll
            for (int e = 0; e < 16; ++e)
                wv[e] = W1[(size_t)ciS[r][e] * CD + i0 + iL];
            #pragma unroll
            for (int e = 0; e < 16; ++e)
                acc = fmaf(cvS[r][e], wv[e], acc);
            if (cnt > 16) {
                const float* cvr = cval + (size_t)(s0 + r) * CD;
                const int* cir = cidx + (size_t)(s0 + r) * CD;
                for (int e = 16; e < cnt; ++e)
                    acc = fmaf(cvr[e], W1[(size_t)cir[e] * CD + i0 + iL], acc);
            }
            hTs[iL][r] = fmaxf(acc, 0.f);
        }
        __syncthreads();
        #pragma unroll 8
        for (int i = 0; i < 64; ++i) {
            float2 h2 = *(const float2*)&hTs[i][2 * tm];
            float4 w4 = *(const float4*)&W2s[i][4 * tn];
            const float* wp = &w4.x;
            #pragma unroll
            for (int j = 0; j < 4; ++j) {
                acc0[j] = fmaf(h2.x, wp[j], acc0[j]);
                acc1[j] = fmaf(h2.y, wp[j], acc1[j]);
            }
        }
    }

    float4 bb = *(const float4*)&b2[4 * tn];
    const float* bp = &bb.x;
    int g0 = perm[s0 + 2 * tm];
    int g1 = perm[s0 + 2 * tm + 1];
    float4 o0, o1;
    #pragma unroll
    for (int j = 0; j < 4; ++j) { (&o0.x)[j] = acc0[j] + bp[j]; (&o1.x)[j] = acc1[j] + bp[j]; }
    *(float4*)&out[(size_t)g0 * PD + 4 * tn] = o0;
    *(float4*)&out[(size_t)g1 * PD + 4 * tn] = o1;
}

extern "C" void kernel_launch(void* const* d_in, const int* in_sizes, int n_in,
                              void* d_out, int out_size, void* d_ws, size_t ws_size,
                              hipStream_t stream) {
    const float* x     = (const float*)d_in[0];
    const float* Wq    = (const float*)d_in[1];
    const float* bq    = (const float*)d_in[2];
    const float* keys  = (const float*)d_in[3];
    const float* We    = (const float*)d_in[4];
    const float* S     = (const float*)d_in[5];
    const float* theta = (const float*)d_in[6];
    const float* W1    = (const float*)d_in[7];
    const float* b1    = (const float*)d_in[8];
    const float* W2    = (const float*)d_in[9];
    const float* b2    = (const float*)d_in[10];
    float* out = (float*)d_out;

    const size_t F = (size_t)NB * CD;  // 8.39M elements
    float* Bx = (float*)d_ws;                         // region 0: F floats
    _Float16* zAh = (_Float16*)(Bx + F);              // region 1: 2F halves
    _Float16* zAl = zAh + F;
    float* R1 = (float*)(zAl + F);                    // region 2: F floats, multi-phase
    //  phase A (pre-G2): x/We split planes
    _Float16* xh  = (_Float16*)R1;
    _Float16* xl  = xh + (size_t)NB * IND;
    _Float16* weh = xl + (size_t)NB * IND;
    _Float16* wel = weh + (size_t)KE * IND * CD;
    //  phase B (G2..G5): zB ping-pong planes
    _Float16* zBh = (_Float16*)R1;
    _Float16* zBl = zBh + F;
    //  phase C (G6..): z1 fp32
    float* z1 = R1;
    _Float16* sth = (_Float16*)(R1 + F);              // region 3: 2F halves
    _Float16* stl = sth + F;
    float* M  = (float*)(stl + F);
    float* sb = M + IND * KE;
    int* idx     = (int*)(sb + 8);
    int* perm    = idx + NB;
    int* counts  = perm + NB;
    int* offsets = counts + KE;
    int* rcnt    = offsets + KE;
    // compact lists alias Bx (cval) and zAh (cidx) — both dead after G6
    float* cval = Bx;
    int*   cidx = (int*)zAh;

    k_split_rows<<<(NB * IND) / 1024, 256, 0, stream>>>(x, xh, xl, NB * IND);
    {
        dim3 g(IND / 64, CD / 64, KE);
        k_tsplit<<<g, 256, 0, stream>>>(We, weh, wel, IND);
    }
    {
        dim3 g(CD / 64, CD / 64, KE);
        k_tsplit<<<g, 256, 0, stream>>>(S, sth, stl, CD);
    }
    k_precompute_M<<<16, 256, 0, stream>>>(Wq, keys, bq, M, sb);
    k_scores<<<NB / 4, 256, 0, stream>>>(x, M, sb, idx);
    k_count<<<1, 256, 0, stream>>>(idx, perm, counts, offsets);

    dim3 gg(CD / 128, NB / 128, KE);
    k_mfma<IND, 0><<<gg, 256, 0, stream>>>(xh, xl, weh, wel, theta, nullptr, Bx, zAh, zAl, nullptr, perm, counts, offsets);
    k_mfma<CD, 1><<<gg, 256, 0, stream>>>(zAh, zAl, sth, stl, theta, Bx, nullptr, zBh, zBl, nullptr, perm, counts, offsets);
    k_mfma<CD, 1><<<gg, 256, 0, stream>>>(zBh, zBl, sth, stl, theta, Bx, nullptr, zAh, zAl, nullptr, perm, counts, offsets);
    k_mfma<CD, 1><<<gg, 256, 0, stream>>>(zAh, zAl, sth, stl, theta, Bx, nullptr, zBh, zBl, nullptr, perm, counts, offsets);
    k_mfma<CD, 1><<<gg, 256, 0, stream>>>(zBh, zBl, sth, stl, theta, Bx, nullptr, zAh, zAl, nullptr, perm, counts, offsets);
    k_mfma<CD, 2><<<gg, 256, 0, stream>>>(zAh, zAl, sth, stl, theta, Bx, nullptr, nullptr, nullptr, z1, perm, counts, offsets);

    k_prune<<<NB, 256, 0, stream>>>(z1, offsets, cval, cidx, rcnt);
    k_output<<<NB / ORB, 256, 0, stream>>>(cval, cidx, rcnt, W1, b1, W2, b2, perm, out);
}

// Round 8
// 765.179 us; speedup vs baseline: 1.5098x; 1.5098x over previous
//
#include <hip/hip_runtime.h>
#include <math.h>

#define NB 8192
#define IND 512
#define QDIM 128
#define CD 1024
#define KE 8
#define PD 64
#define ORB 32  // rows per k_output block

typedef _Float16 h8 __attribute__((ext_vector_type(8)));
typedef _Float16 h4 __attribute__((ext_vector_type(4)));
typedef float fx16 __attribute__((ext_vector_type(16)));

#define GLD16(g, l) __builtin_amdgcn_global_load_lds((const __attribute__((address_space(1))) void*)(g), (__attribute__((address_space(3))) void*)(l), 16, 0, 0)

__device__ __forceinline__ float softt(float v, float th) {
    float a = fabsf(v) - th;
    return a > 0.0f ? copysignf(a, v) : 0.0f;
}

// ---------------- split helpers: v = hi + lo * 2^-11 (lo stored pre-scaled by 2048)
__device__ __forceinline__ void fsplit(float v, _Float16& hi, _Float16& lo) {
    hi = (_Float16)v;
    lo = (_Float16)((v - (float)hi) * 2048.0f);
}

// ---------------- K0: M = Wq @ keys^T / sqrt(QDIM), sb = bq @ keys^T / sqrt(QDIM)
__global__ void k_precompute_M(const float* __restrict__ Wq, const float* __restrict__ keys,
                               const float* __restrict__ bq, float* __restrict__ M,
                               float* __restrict__ sb) {
    const float RSQ = 0.088388347648318447f; // 1/sqrt(128)
    int g = blockIdx.x * 256 + threadIdx.x;  // 0..4095
    if (g < IND * KE) {
        int i = g >> 3, k = g & 7;
        float s = 0.f;
        for (int q = 0; q < QDIM; ++q) s += Wq[i * QDIM + q] * keys[k * QDIM + q];
        M[g] = s * RSQ;  // M[i*8+k]
    }
    if (blockIdx.x == 0 && threadIdx.x < KE) {
        int k = threadIdx.x;
        float s = 0.f;
        for (int q = 0; q < QDIM; ++q) s += bq[q] * keys[k * QDIM + q];
        sb[k] = s * RSQ;
    }
}

// ---------------- K1: per-row scores -> expert idx (one wave per row, no atomics)
__global__ __launch_bounds__(256)
void k_scores(const float* __restrict__ x, const float* __restrict__ M,
              const float* __restrict__ sb, int* __restrict__ idx) {
    __shared__ float Ms[KE][IND];
    __shared__ float sbs[KE];
    int t = threadIdx.x;
    #pragma unroll
    for (int j = 0; j < 16; ++j) {
        int e = j * 256 + t;
        Ms[e & 7][e >> 3] = M[e];
    }
    if (t < KE) sbs[t] = sb[t];
    __syncthreads();
    int w = t >> 6, lane = t & 63;
    int row = blockIdx.x * 4 + w;
    const float* xr = x + (size_t)row * IND;
    float sc[KE];
    #pragma unroll
    for (int k = 0; k < KE; ++k) sc[k] = 0.f;
    #pragma unroll
    for (int j = 0; j < IND / 64; ++j) {
        int ii = lane + 64 * j;
        float xv = xr[ii];
        #pragma unroll
        for (int k = 0; k < KE; ++k) sc[k] += xv * Ms[k][ii];
    }
    #pragma unroll
    for (int k = 0; k < KE; ++k) {
        #pragma unroll
        for (int off = 32; off >= 1; off >>= 1) sc[k] += __shfl_down(sc[k], off, 64);
    }
    if (lane == 0) {
        float smax = -1e30f;
        #pragma unroll
        for (int k = 0; k < KE; ++k) { sc[k] += sbs[k]; smax = fmaxf(smax, sc[k]); }
        const float LN09 = -0.105360515657826301f;  // ln(0.9)
        int e = 0;
        #pragma unroll
        for (int k = KE - 1; k >= 0; --k)
            if (sc[k] >= smax + LN09) e = k;  // smallest eligible k (sl is increasing)
        idx[row] = e;
    }
}

// ---------------- K2: single-block counting sort: counts, offsets, perm (no global atomics)
__global__ __launch_bounds__(256)
void k_count(const int* __restrict__ idx, int* __restrict__ perm,
             int* __restrict__ counts, int* __restrict__ offsets) {
    __shared__ int hist[256][KE];      // 8 KB
    __shared__ int sc[2][KE][256];     // 16 KB ping-pong scan
    __shared__ int base[KE];
    const int t = threadIdx.x;
    int pc[KE];
    #pragma unroll
    for (int e = 0; e < KE; ++e) pc[e] = 0;
    for (int j = 0; j < NB / 256; ++j) pc[idx[j * 256 + t]]++;
    #pragma unroll
    for (int e = 0; e < KE; ++e) { hist[t][e] = pc[e]; sc[0][e][t] = pc[e]; }
    __syncthreads();
    int cur = 0;
    for (int d = 1; d < 256; d <<= 1) {
        #pragma unroll
        for (int e = 0; e < KE; ++e) {
            int v = sc[cur][e][t];
            if (t >= d) v += sc[cur][e][t - d];
            sc[cur ^ 1][e][t] = v;
        }
        cur ^= 1;
        __syncthreads();
    }
    if (t == 0) {
        int a = 0;
        #pragma unroll
        for (int e = 0; e < KE; ++e) {
            int tot = sc[cur][e][255];
            base[e] = a; offsets[e] = a; counts[e] = tot; a += tot;
        }
    }
    __syncthreads();
    int pos[KE];
    #pragma unroll
    for (int e = 0; e < KE; ++e) pos[e] = base[e] + sc[cur][e][t] - hist[t][e];
    for (int j = 0; j < NB / 256; ++j) {
        int r = j * 256 + t;
        int e = idx[r];
        perm[pos[e]++] = r;
    }
}

// ---------------- K4: elementwise split of x into hi/lo fp16 planes
__global__ __launch_bounds__(256)
void k_split_rows(const float* __restrict__ src, _Float16* __restrict__ ph,
                  _Float16* __restrict__ pl, int n) {
    int i = (blockIdx.x * 256 + threadIdx.x) * 4;
    if (i < n) {
        float4 v = *(const float4*)(src + i);
        h4 hh, ll;
        #pragma unroll
        for (int j = 0; j < 4; ++j) {
            _Float16 a, b;
            fsplit((&v.x)[j], a, b);
            hh[j] = a; ll[j] = b;
        }
        *(h4*)(ph + i) = hh;
        *(h4*)(pl + i) = ll;
    }
}

// ---------------- K5: transpose+split: src[e][K][CD] fp32 -> th/tl[e][CD][K] fp16
__global__ __launch_bounds__(256)
void k_tsplit(const float* __restrict__ src, _Float16* __restrict__ th,
              _Float16* __restrict__ tl, int K) {
    __shared__ float tile[64][65];
    int e = blockIdx.z;
    int k0 = blockIdx.x * 64;
    int n0 = blockIdx.y * 64;
    const float* s = src + (size_t)e * K * CD;
    int t = threadIdx.x;
    int tr = t >> 4;
    int tc = (t & 15) * 4;
    #pragma unroll
    for (int p = 0; p < 4; ++p) {
        int kk = tr + p * 16;
        float4 v = *(const float4*)&s[(size_t)(k0 + kk) * CD + n0 + tc];
        #pragma unroll
        for (int j = 0; j < 4; ++j) tile[kk][tc + j] = (&v.x)[j];
    }
    __syncthreads();
    int n = t >> 2;
    int kq = (t & 3) * 16;
    h8 hh0, hh1, ll0, ll1;
    #pragma unroll
    for (int j = 0; j < 8; ++j) {
        _Float16 a, b;
        fsplit(tile[kq + j][n], a, b);
        hh0[j] = a; ll0[j] = b;
        fsplit(tile[kq + 8 + j][n], a, b);
        hh1[j] = a; ll1[j] = b;
    }
    size_t ob = ((size_t)e * CD + n0 + n) * K + k0 + kq;
    *(h8*)(th + ob) = hh0;
    *(h8*)(th + ob + 8) = hh1;
    *(h8*)(tl + ob) = ll0;
    *(h8*)(tl + ob + 8) = ll1;
}

// ---------------- grouped split-fp16 MFMA GEMM, 128x128 tile, BK=32 k-values,
// double-buffered async staging (one barrier/iter) + XCD swizzle.  [R6 structure:
// 64KB LDS -> 2 blocks/CU, NO min-waves bound — (256,3) in R7 spilled accumulators
// to scratch (VGPR 84, WRITE_SIZE 211MB) and regressed 2x.]
// A planes: [row][KDIM] fp16 hi/lo (lo pre-scaled 2048). B planes: [e][CD][KDIM] K-major.
// LDS row: 8 chunks of 16B; physical chunk = logical ^ (row&7); logical lc = kg*2+comp.
// acc1 = hi*hi; acc2 = hi*lo' + lo'*hi; result = acc1 + acc2*2^-11 (rel err 2^-22).
template <int KDIM, int MODE>
__global__ __launch_bounds__(256)
void k_mfma(const _Float16* __restrict__ Ah, const _Float16* __restrict__ Al,
            const _Float16* __restrict__ Bh, const _Float16* __restrict__ Bl,
            const float* __restrict__ theta, const float* __restrict__ BxBuf,
            float* __restrict__ BxOut, _Float16* __restrict__ zh, _Float16* __restrict__ zl,
            float* __restrict__ zf,
            const int* __restrict__ perm, const int* __restrict__ counts,
            const int* __restrict__ offsets) {
    const int e = blockIdx.z;
    const int cnt = counts[e];
    const int p = blockIdx.x + 8 * blockIdx.y;
    const int gx = p & 7;
    const int qq = p >> 3;
    const int bxl = qq & 7;
    const int byl = gx + 8 * (qq >> 3);
    const int m0 = byl * 128;
    if (m0 >= cnt) return;
    const int n0 = bxl * 128;
    const int off = offsets[e];
    const float th = theta[e];

    __shared__ _Float16 Asl[2][128 * 64];  // 16 KB per buffer
    __shared__ _Float16 Bsl[2][128 * 64];

    const int t = threadIdx.x;
    const int lane = t & 63;
    const int w = t >> 6;

    const _Float16* aptr[4];
    const _Float16* bptr[4];
    #pragma unroll
    for (int i = 0; i < 4; ++i) {
        int s = w * 4 + i;
        int r = s * 8 + (lane >> 3);
        int pc = lane & 7;
        int lc = pc ^ (r & 7);
        int comp = lc & 1;
        int kg = lc >> 1;
        int mrow = m0 + r; if (mrow > cnt - 1) mrow = cnt - 1;
        size_t grow;
        if constexpr (MODE == 0) grow = (size_t)perm[off + mrow];
        else grow = (size_t)(off + mrow);
        aptr[i] = (comp ? Al : Ah) + grow * KDIM + kg * 8;
        bptr[i] = (comp ? Bl : Bh) + ((size_t)e * CD + n0 + r) * KDIM + kg * 8;
    }

    const int wm = w >> 1, wn = w & 1;
    const int q = lane >> 5;
    const int ml = lane & 31;
    const int sw = ml & 7;

    fx16 acc1[2][2], acc2[2][2];
    #pragma unroll
    for (int mt = 0; mt < 2; ++mt)
        #pragma unroll
        for (int nt = 0; nt < 2; ++nt)
            #pragma unroll
            for (int g = 0; g < 16; ++g) { acc1[mt][nt][g] = 0.f; acc2[mt][nt][g] = 0.f; }

    auto stage = [&](int kt, int buf) {
        const int koff = kt * 32;
        #pragma unroll
        for (int i = 0; i < 4; ++i) {
            GLD16(aptr[i] + koff, &Asl[buf][(w * 4 + i) * 512]);
            GLD16(bptr[i] + koff, &Bsl[buf][(w * 4 + i) * 512]);
        }
    };

    const int NT = KDIM / 32;
    stage(0, 0);
    __syncthreads();
    for (int kt = 0; kt < NT; ++kt) {
        const int buf = kt & 1;
        if (kt + 1 < NT) stage(kt + 1, buf ^ 1);  // prefetch in flight during compute
        #pragma unroll
        for (int ks = 0; ks < 2; ++ks) {
            const int base = ks * 4 + q * 2;
            h8 ah[2], al2[2], bh2[2], bl2[2];
            #pragma unroll
            for (int mt = 0; mt < 2; ++mt) {
                int mb = (wm * 64 + mt * 32 + ml) * 64;
                ah[mt]  = *(const h8*)&Asl[buf][mb + (((base + 0) ^ sw) * 8)];
                al2[mt] = *(const h8*)&Asl[buf][mb + (((base + 1) ^ sw) * 8)];
            }
            #pragma unroll
            for (int nt = 0; nt < 2; ++nt) {
                int nb = (wn * 64 + nt * 32 + ml) * 64;
                bh2[nt] = *(const h8*)&Bsl[buf][nb + (((base + 0) ^ sw) * 8)];
                bl2[nt] = *(const h8*)&Bsl[buf][nb + (((base + 1) ^ sw) * 8)];
            }
            #pragma unroll
            for (int mt = 0; mt < 2; ++mt)
                #pragma unroll
                for (int nt = 0; nt < 2; ++nt) {
                    acc1[mt][nt] = __builtin_amdgcn_mfma_f32_32x32x16_f16(ah[mt],  bh2[nt], acc1[mt][nt], 0, 0, 0);
                    acc2[mt][nt] = __builtin_amdgcn_mfma_f32_32x32x16_f16(ah[mt],  bl2[nt], acc2[mt][nt], 0, 0, 0);
                    acc2[mt][nt] = __builtin_amdgcn_mfma_f32_32x32x16_f16(al2[mt], bh2[nt], acc2[mt][nt], 0, 0, 0);
                }
        }
        __syncthreads();  // drains prefetch after compute + protects buf reuse
    }

    // epilogue: C/D layout col=lane&31, row=(g&3)+8*(g>>2)+4*q  [m74/m101]
    const float LSC = 4.8828125e-4f;  // 2^-11
    #pragma unroll
    for (int mt = 0; mt < 2; ++mt)
        #pragma unroll
        for (int nt = 0; nt < 2; ++nt) {
            #pragma unroll
            for (int g = 0; g < 16; ++g) {
                int rl = wm * 64 + mt * 32 + (g & 3) + 8 * (g >> 2) + 4 * q;
                int mrow = m0 + rl;
                if (mrow < cnt) {
                    int col = n0 + wn * 64 + nt * 32 + ml;
                    size_t addr = (size_t)(off + mrow) * CD + col;
                    float v = acc1[mt][nt][g] + acc2[mt][nt][g] * LSC;
                    if constexpr (MODE == 0) {
                        BxOut[addr] = v;
                        float z = softt(v, th);
                        _Float16 a, b;
                        fsplit(z, a, b);
                        zh[addr] = a; zl[addr] = b;
                    } else if constexpr (MODE == 1) {
                        float z = softt(v + BxBuf[addr], th);
                        _Float16 a, b;
                        fsplit(z, a, b);
                        zh[addr] = a; zl[addr] = b;
                    } else {
                        zf[addr] = softt(v + BxBuf[addr], th);
                    }
                }
            }
        }
}

// ---------------- K6: per-row top-k threshold (bit search), emit compact (val,idx) lists
__global__ __launch_bounds__(256)
void k_prune(const float* __restrict__ z, const int* __restrict__ offsets,
             float* __restrict__ cval, int* __restrict__ cidx, int* __restrict__ rcnt) {
    __shared__ int red[4];
    __shared__ int wcnt;
    const int SL[KE] = {5, 150, 296, 441, 587, 732, 878, 1024};
    int slot = blockIdx.x;
    int k = 0;
    #pragma unroll
    for (int e = 1; e < KE; ++e)
        if (slot >= offsets[e]) k = e;
    int lvl = SL[k];
    int t = threadIdx.x;
    if (t == 0) wcnt = 0;
    const float* zr = z + (size_t)slot * CD;
    float v[4];
    unsigned ab[4];
    #pragma unroll
    for (int j = 0; j < 4; ++j) {
        v[j] = zr[t + 256 * j];
        ab[j] = __float_as_uint(fabsf(v[j]));
    }
    unsigned thr = 0;
    for (int b = 30; b >= 0; --b) {
        unsigned cand = thr | (1u << b);
        int c = 0;
        #pragma unroll
        for (int j = 0; j < 4; ++j) c += (ab[j] >= cand) ? 1 : 0;
        #pragma unroll
        for (int off = 32; off >= 1; off >>= 1) c += __shfl_down(c, off, 64);
        if ((t & 63) == 0) red[t >> 6] = c;
        __syncthreads();
        int tot = red[0] + red[1] + red[2] + red[3];
        if (tot >= lvl) thr = cand;
        __syncthreads();
    }
    float* cvr = cval + (size_t)slot * CD;
    int* cir = cidx + (size_t)slot * CD;
    #pragma unroll
    for (int j = 0; j < 4; ++j) {
        if (ab[j] >= thr) {
            int p = atomicAdd(&wcnt, 1);
            cvr[p] = v[j];
            cir[p] = t + 256 * j;
        }
    }
    __syncthreads();
    if (t == 0) rcnt[slot] = wcnt;
}

// ---------------- K7: out = relu(h) @ W2 + b2, h = b1 + sparse_z @ W1 (compact lists)
__global__ __launch_bounds__(256)
void k_output(const float* __restrict__ cval, const int* __restrict__ cidx,
              const int* __restrict__ rcnt,
              const float* __restrict__ W1, const float* __restrict__ b1,
              const float* __restrict__ W2, const float* __restrict__ b2,
              const int* __restrict__ perm, float* __restrict__ out) {
    __shared__ float W2s[64][68];
    __shared__ float hTs[64][34];
    __shared__ float cvS[ORB][16];
    __shared__ int   ciS[ORB][16];
    __shared__ int   cnS[ORB];

    const int t = threadIdx.x;
    const int s0 = blockIdx.x * ORB;

    if (t < ORB) cnS[t] = rcnt[s0 + t];
    __syncthreads();
    #pragma unroll
    for (int u = t; u < ORB * 16; u += 256) {
        int r = u >> 4, e = u & 15;
        int cnt = cnS[r];
        cvS[r][e] = (e < cnt) ? cval[(size_t)(s0 + r) * CD + e] : 0.f;
        ciS[r][e] = (e < cnt) ? cidx[(size_t)(s0 + r) * CD + e] : 0;
    }

    const int tm = t >> 4;
    const int tn = t & 15;
    const int iL = t & 63;
    const int rs = t >> 6;

    float acc0[4], acc1[4];
    #pragma unroll
    for (int j = 0; j < 4; ++j) { acc0[j] = 0.f; acc1[j] = 0.f; }

    for (int ch = 0; ch < 16; ++ch) {
        const int i0 = ch * 64;
        __syncthreads();
        #pragma unroll
        for (int p = 0; p < 4; ++p) {
            int kr = (t >> 4) + 16 * p;
            float4 w = *(const float4*)&W2[(size_t)(i0 + kr) * PD + (t & 15) * 4];
            *(float4*)&W2s[kr][(t & 15) * 4] = w;
        }
        float bv = b1[i0 + iL];
        #pragma unroll
        for (int jj = 0; jj < 8; ++jj) {
            int r = rs * 8 + jj;
            int cnt = cnS[r];
            float acc = bv;
            float wv[16];
            #pragma unroll
            for (int e = 0; e < 16; ++e)
                wv[e] = W1[(size_t)ciS[r][e] * CD + i0 + iL];
            #pragma unroll
            for (int e = 0; e < 16; ++e)
                acc = fmaf(cvS[r][e], wv[e], acc);
            if (cnt > 16) {
                const float* cvr = cval + (size_t)(s0 + r) * CD;
                const int* cir = cidx + (size_t)(s0 + r) * CD;
                for (int e = 16; e < cnt; ++e)
                    acc = fmaf(cvr[e], W1[(size_t)cir[e] * CD + i0 + iL], acc);
            }
            hTs[iL][r] = fmaxf(acc, 0.f);
        }
        __syncthreads();
        #pragma unroll 8
        for (int i = 0; i < 64; ++i) {
            float2 h2 = *(const float2*)&hTs[i][2 * tm];
            float4 w4 = *(const float4*)&W2s[i][4 * tn];
            const float* wp = &w4.x;
            #pragma unroll
            for (int j = 0; j < 4; ++j) {
                acc0[j] = fmaf(h2.x, wp[j], acc0[j]);
                acc1[j] = fmaf(h2.y, wp[j], acc1[j]);
            }
        }
    }

    float4 bb = *(const float4*)&b2[4 * tn];
    const float* bp = &bb.x;
    int g0 = perm[s0 + 2 * tm];
    int g1 = perm[s0 + 2 * tm + 1];
    float4 o0, o1;
    #pragma unroll
    for (int j = 0; j < 4; ++j) { (&o0.x)[j] = acc0[j] + bp[j]; (&o1.x)[j] = acc1[j] + bp[j]; }
    *(float4*)&out[(size_t)g0 * PD + 4 * tn] = o0;
    *(float4*)&out[(size_t)g1 * PD + 4 * tn] = o1;
}

extern "C" void kernel_launch(void* const* d_in, const int* in_sizes, int n_in,
                              void* d_out, int out_size, void* d_ws, size_t ws_size,
                              hipStream_t stream) {
    const float* x     = (const float*)d_in[0];
    const float* Wq    = (const float*)d_in[1];
    const float* bq    = (const float*)d_in[2];
    const float* keys  = (const float*)d_in[3];
    const float* We    = (const float*)d_in[4];
    const float* S     = (const float*)d_in[5];
    const float* theta = (const float*)d_in[6];
    const float* W1    = (const float*)d_in[7];
    const float* b1    = (const float*)d_in[8];
    const float* W2    = (const float*)d_in[9];
    const float* b2    = (const float*)d_in[10];
    float* out = (float*)d_out;

    const size_t F = (size_t)NB * CD;  // 8.39M elements
    float* Bx = (float*)d_ws;                         // region 0: F floats
    _Float16* zAh = (_Float16*)(Bx + F);              // region 1: 2F halves
    _Float16* zAl = zAh + F;
    float* R1 = (float*)(zAl + F);                    // region 2: F floats, multi-phase
    _Float16* xh  = (_Float16*)R1;
    _Float16* xl  = xh + (size_t)NB * IND;
    _Float16* weh = xl + (size_t)NB * IND;
    _Float16* wel = weh + (size_t)KE * IND * CD;
    _Float16* zBh = (_Float16*)R1;
    _Float16* zBl = zBh + F;
    float* z1 = R1;
    _Float16* sth = (_Float16*)(R1 + F);              // region 3: 2F halves
    _Float16* stl = sth + F;
    float* M  = (float*)(stl + F);
    float* sb = M + IND * KE;
    int* idx     = (int*)(sb + 8);
    int* perm    = idx + NB;
    int* counts  = perm + NB;
    int* offsets = counts + KE;
    int* rcnt    = offsets + KE;
    float* cval = Bx;
    int*   cidx = (int*)zAh;

    k_split_rows<<<(NB * IND) / 1024, 256, 0, stream>>>(x, xh, xl, NB * IND);
    {
        dim3 g(IND / 64, CD / 64, KE);
        k_tsplit<<<g, 256, 0, stream>>>(We, weh, wel, IND);
    }
    {
        dim3 g(CD / 64, CD / 64, KE);
        k_tsplit<<<g, 256, 0, stream>>>(S, sth, stl, CD);
    }
    k_precompute_M<<<16, 256, 0, stream>>>(Wq, keys, bq, M, sb);
    k_scores<<<NB / 4, 256, 0, stream>>>(x, M, sb, idx);
    k_count<<<1, 256, 0, stream>>>(idx, perm, counts, offsets);

    dim3 gg(CD / 128, NB / 128, KE);
    k_mfma<IND, 0><<<gg, 256, 0, stream>>>(xh, xl, weh, wel, theta, nullptr, Bx, zAh, zAl, nullptr, perm, counts, offsets);
    k_mfma<CD, 1><<<gg, 256, 0, stream>>>(zAh, zAl, sth, stl, theta, Bx, nullptr, zBh, zBl, nullptr, perm, counts, offsets);
    k_mfma<CD, 1><<<gg, 256, 0, stream>>>(zBh, zBl, sth, stl, theta, Bx, nullptr, zAh, zAl, nullptr, perm, counts, offsets);
    k_mfma<CD, 1><<<gg, 256, 0, stream>>>(zAh, zAl, sth, stl, theta, Bx, nullptr, zBh, zBl, nullptr, perm, counts, offsets);
    k_mfma<CD, 1><<<gg, 256, 0, stream>>>(zBh, zBl, sth, stl, theta, Bx, nullptr, zAh, zAl, nullptr, perm, counts, offsets);
    k_mfma<CD, 2><<<gg, 256, 0, stream>>>(zAh, zAl, sth, stl, theta, Bx, nullptr, nullptr, nullptr, z1, perm, counts, offsets);

    k_prune<<<NB, 256, 0, stream>>>(z1, offsets, cval, cidx, rcnt);
    k_output<<<NB / ORB, 256, 0, stream>>>(cval, cidx, rcnt, W1, b1, W2, b2, perm, out);
}

// Round 9
// 679.662 us; speedup vs baseline: 1.6997x; 1.1258x over previous
//
#include <hip/hip_runtime.h>
#include <math.h>

#define NB 8192
#define IND 512
#define QDIM 128
#define CD 1024
#define KE 8
#define PD 64
#define ORB 32  // rows per k_output block

typedef _Float16 h8 __attribute__((ext_vector_type(8)));
typedef _Float16 h4 __attribute__((ext_vector_type(4)));
typedef float fx16 __attribute__((ext_vector_type(16)));

#define GLD16(g, l) __builtin_amdgcn_global_load_lds((const __attribute__((address_space(1))) void*)(g), (__attribute__((address_space(3))) void*)(l), 16, 0, 0)

__device__ __forceinline__ float softt(float v, float th) {
    float a = fabsf(v) - th;
    return a > 0.0f ? copysignf(a, v) : 0.0f;
}

// ---------------- split helpers: v = hi + lo * 2^-11 (lo stored pre-scaled by 2048)
__device__ __forceinline__ void fsplit(float v, _Float16& hi, _Float16& lo) {
    hi = (_Float16)v;
    lo = (_Float16)((v - (float)hi) * 2048.0f);
}

// ---------------- K0: M = Wq @ keys^T / sqrt(QDIM), sb = bq @ keys^T / sqrt(QDIM)
__global__ void k_precompute_M(const float* __restrict__ Wq, const float* __restrict__ keys,
                               const float* __restrict__ bq, float* __restrict__ M,
                               float* __restrict__ sb) {
    const float RSQ = 0.088388347648318447f; // 1/sqrt(128)
    int g = blockIdx.x * 256 + threadIdx.x;  // 0..4095
    if (g < IND * KE) {
        int i = g >> 3, k = g & 7;
        float s = 0.f;
        for (int q = 0; q < QDIM; ++q) s += Wq[i * QDIM + q] * keys[k * QDIM + q];
        M[g] = s * RSQ;  // M[i*8+k]
    }
    if (blockIdx.x == 0 && threadIdx.x < KE) {
        int k = threadIdx.x;
        float s = 0.f;
        for (int q = 0; q < QDIM; ++q) s += bq[q] * keys[k * QDIM + q];
        sb[k] = s * RSQ;
    }
}

// ---------------- K1: per-row scores -> expert idx (one wave per row, no atomics)
__global__ __launch_bounds__(256)
void k_scores(const float* __restrict__ x, const float* __restrict__ M,
              const float* __restrict__ sb, int* __restrict__ idx) {
    __shared__ float Ms[KE][IND];
    __shared__ float sbs[KE];
    int t = threadIdx.x;
    #pragma unroll
    for (int j = 0; j < 16; ++j) {
        int e = j * 256 + t;
        Ms[e & 7][e >> 3] = M[e];
    }
    if (t < KE) sbs[t] = sb[t];
    __syncthreads();
    int w = t >> 6, lane = t & 63;
    int row = blockIdx.x * 4 + w;
    const float* xr = x + (size_t)row * IND;
    float sc[KE];
    #pragma unroll
    for (int k = 0; k < KE; ++k) sc[k] = 0.f;
    #pragma unroll
    for (int j = 0; j < IND / 64; ++j) {
        int ii = lane + 64 * j;
        float xv = xr[ii];
        #pragma unroll
        for (int k = 0; k < KE; ++k) sc[k] += xv * Ms[k][ii];
    }
    #pragma unroll
    for (int k = 0; k < KE; ++k) {
        #pragma unroll
        for (int off = 32; off >= 1; off >>= 1) sc[k] += __shfl_down(sc[k], off, 64);
    }
    if (lane == 0) {
        float smax = -1e30f;
        #pragma unroll
        for (int k = 0; k < KE; ++k) { sc[k] += sbs[k]; smax = fmaxf(smax, sc[k]); }
        const float LN09 = -0.105360515657826301f;  // ln(0.9)
        int e = 0;
        #pragma unroll
        for (int k = KE - 1; k >= 0; --k)
            if (sc[k] >= smax + LN09) e = k;  // smallest eligible k (sl is increasing)
        idx[row] = e;
    }
}

// ---------------- K2: single-block counting sort: counts, offsets, perm (no global atomics)
__global__ __launch_bounds__(256)
void k_count(const int* __restrict__ idx, int* __restrict__ perm,
             int* __restrict__ counts, int* __restrict__ offsets) {
    __shared__ int hist[256][KE];      // 8 KB
    __shared__ int sc[2][KE][256];     // 16 KB ping-pong scan
    __shared__ int base[KE];
    const int t = threadIdx.x;
    int pc[KE];
    #pragma unroll
    for (int e = 0; e < KE; ++e) pc[e] = 0;
    for (int j = 0; j < NB / 256; ++j) pc[idx[j * 256 + t]]++;
    #pragma unroll
    for (int e = 0; e < KE; ++e) { hist[t][e] = pc[e]; sc[0][e][t] = pc[e]; }
    __syncthreads();
    int cur = 0;
    for (int d = 1; d < 256; d <<= 1) {
        #pragma unroll
        for (int e = 0; e < KE; ++e) {
            int v = sc[cur][e][t];
            if (t >= d) v += sc[cur][e][t - d];
            sc[cur ^ 1][e][t] = v;
        }
        cur ^= 1;
        __syncthreads();
    }
    if (t == 0) {
        int a = 0;
        #pragma unroll
        for (int e = 0; e < KE; ++e) {
            int tot = sc[cur][e][255];
            base[e] = a; offsets[e] = a; counts[e] = tot; a += tot;
        }
    }
    __syncthreads();
    int pos[KE];
    #pragma unroll
    for (int e = 0; e < KE; ++e) pos[e] = base[e] + sc[cur][e][t] - hist[t][e];
    for (int j = 0; j < NB / 256; ++j) {
        int r = j * 256 + t;
        int e = idx[r];
        perm[pos[e]++] = r;
    }
}

// ---------------- K4: elementwise split of x into hi/lo fp16 planes
__global__ __launch_bounds__(256)
void k_split_rows(const float* __restrict__ src, _Float16* __restrict__ ph,
                  _Float16* __restrict__ pl, int n) {
    int i = (blockIdx.x * 256 + threadIdx.x) * 4;
    if (i < n) {
        float4 v = *(const float4*)(src + i);
        h4 hh, ll;
        #pragma unroll
        for (int j = 0; j < 4; ++j) {
            _Float16 a, b;
            fsplit((&v.x)[j], a, b);
            hh[j] = a; ll[j] = b;
        }
        *(h4*)(ph + i) = hh;
        *(h4*)(pl + i) = ll;
    }
}

// ---------------- K5: transpose+split: src[e][K][CD] fp32 -> th/tl[e][CD][K] fp16
// Skips experts with zero selected rows (counts from k_count — launch-ordered before).
__global__ __launch_bounds__(256)
void k_tsplit(const float* __restrict__ src, _Float16* __restrict__ th,
              _Float16* __restrict__ tl, int K, const int* __restrict__ counts) {
    int e = blockIdx.z;
    if (counts[e] == 0) return;  // expert never used downstream
    __shared__ float tile[64][65];
    int k0 = blockIdx.x * 64;
    int n0 = blockIdx.y * 64;
    const float* s = src + (size_t)e * K * CD;
    int t = threadIdx.x;
    int tr = t >> 4;
    int tc = (t & 15) * 4;
    #pragma unroll
    for (int p = 0; p < 4; ++p) {
        int kk = tr + p * 16;
        float4 v = *(const float4*)&s[(size_t)(k0 + kk) * CD + n0 + tc];
        #pragma unroll
        for (int j = 0; j < 4; ++j) tile[kk][tc + j] = (&v.x)[j];
    }
    __syncthreads();
    int n = t >> 2;
    int kq = (t & 3) * 16;
    h8 hh0, hh1, ll0, ll1;
    #pragma unroll
    for (int j = 0; j < 8; ++j) {
        _Float16 a, b;
        fsplit(tile[kq + j][n], a, b);
        hh0[j] = a; ll0[j] = b;
        fsplit(tile[kq + 8 + j][n], a, b);
        hh1[j] = a; ll1[j] = b;
    }
    size_t ob = ((size_t)e * CD + n0 + n) * K + k0 + kq;
    *(h8*)(th + ob) = hh0;
    *(h8*)(th + ob + 8) = hh1;
    *(h8*)(tl + ob) = ll0;
    *(h8*)(tl + ob + 8) = ll1;
}

// ---------------- grouped split-fp16 MFMA GEMM, 128x128 tile, BK=32 k-values,
// double-buffered async staging (one barrier/iter) + XCD swizzle.
// [R6 structure: 64KB LDS -> 2 blocks/CU, NO min-waves bound — (256,3) spilled.]
// Bank swizzle g(r) = (r ^ (r>>3)) & 7: rows differing by 8 hit different bank
// groups (plain r&7 gave systematic 2-way b128 conflicts: 4.19M cycles/dispatch).
// acc1 = hi*hi; acc2 = hi*lo' + lo'*hi; result = acc1 + acc2*2^-11 (rel err 2^-22).
template <int KDIM, int MODE>
__global__ __launch_bounds__(256)
void k_mfma(const _Float16* __restrict__ Ah, const _Float16* __restrict__ Al,
            const _Float16* __restrict__ Bh, const _Float16* __restrict__ Bl,
            const float* __restrict__ theta, const float* __restrict__ BxBuf,
            float* __restrict__ BxOut, _Float16* __restrict__ zh, _Float16* __restrict__ zl,
            float* __restrict__ zf,
            const int* __restrict__ perm, const int* __restrict__ counts,
            const int* __restrict__ offsets) {
    const int e = blockIdx.z;
    const int cnt = counts[e];
    const int p = blockIdx.x + 8 * blockIdx.y;
    const int gx = p & 7;
    const int qq = p >> 3;
    const int bxl = qq & 7;
    const int byl = gx + 8 * (qq >> 3);
    const int m0 = byl * 128;
    if (m0 >= cnt) return;
    const int n0 = bxl * 128;
    const int off = offsets[e];
    const float th = theta[e];

    __shared__ _Float16 Asl[2][128 * 64];  // 16 KB per buffer
    __shared__ _Float16 Bsl[2][128 * 64];

    const int t = threadIdx.x;
    const int lane = t & 63;
    const int w = t >> 6;

    const _Float16* aptr[4];
    const _Float16* bptr[4];
    #pragma unroll
    for (int i = 0; i < 4; ++i) {
        int s = w * 4 + i;
        int r = s * 8 + (lane >> 3);
        int pc = lane & 7;
        int lc = pc ^ ((r ^ (r >> 3)) & 7);
        int comp = lc & 1;
        int kg = lc >> 1;
        int mrow = m0 + r; if (mrow > cnt - 1) mrow = cnt - 1;
        size_t grow;
        if constexpr (MODE == 0) grow = (size_t)perm[off + mrow];
        else grow = (size_t)(off + mrow);
        aptr[i] = (comp ? Al : Ah) + grow * KDIM + kg * 8;
        bptr[i] = (comp ? Bl : Bh) + ((size_t)e * CD + n0 + r) * KDIM + kg * 8;
    }

    const int wm = w >> 1, wn = w & 1;
    const int q = lane >> 5;
    const int ml = lane & 31;

    fx16 acc1[2][2], acc2[2][2];
    #pragma unroll
    for (int mt = 0; mt < 2; ++mt)
        #pragma unroll
        for (int nt = 0; nt < 2; ++nt)
            #pragma unroll
            for (int g = 0; g < 16; ++g) { acc1[mt][nt][g] = 0.f; acc2[mt][nt][g] = 0.f; }

    auto stage = [&](int kt, int buf) {
        const int koff = kt * 32;
        #pragma unroll
        for (int i = 0; i < 4; ++i) {
            GLD16(aptr[i] + koff, &Asl[buf][(w * 4 + i) * 512]);
            GLD16(bptr[i] + koff, &Bsl[buf][(w * 4 + i) * 512]);
        }
    };

    const int NT = KDIM / 32;
    stage(0, 0);
    __syncthreads();
    for (int kt = 0; kt < NT; ++kt) {
        const int buf = kt & 1;
        if (kt + 1 < NT) stage(kt + 1, buf ^ 1);  // prefetch in flight during compute
        #pragma unroll
        for (int ks = 0; ks < 2; ++ks) {
            const int base = ks * 4 + q * 2;
            h8 ah[2], al2[2], bh2[2], bl2[2];
            #pragma unroll
            for (int mt = 0; mt < 2; ++mt) {
                int row = wm * 64 + mt * 32 + ml;
                int sw = (row ^ (row >> 3)) & 7;
                int mb = row * 64;
                ah[mt]  = *(const h8*)&Asl[buf][mb + (((base + 0) ^ sw) * 8)];
                al2[mt] = *(const h8*)&Asl[buf][mb + (((base + 1) ^ sw) * 8)];
            }
            #pragma unroll
            for (int nt = 0; nt < 2; ++nt) {
                int col = wn * 64 + nt * 32 + ml;
                int sw = (col ^ (col >> 3)) & 7;
                int nb = col * 64;
                bh2[nt] = *(const h8*)&Bsl[buf][nb + (((base + 0) ^ sw) * 8)];
                bl2[nt] = *(const h8*)&Bsl[buf][nb + (((base + 1) ^ sw) * 8)];
            }
            #pragma unroll
            for (int mt = 0; mt < 2; ++mt)
                #pragma unroll
                for (int nt = 0; nt < 2; ++nt) {
                    acc1[mt][nt] = __builtin_amdgcn_mfma_f32_32x32x16_f16(ah[mt],  bh2[nt], acc1[mt][nt], 0, 0, 0);
                    acc2[mt][nt] = __builtin_amdgcn_mfma_f32_32x32x16_f16(ah[mt],  bl2[nt], acc2[mt][nt], 0, 0, 0);
                    acc2[mt][nt] = __builtin_amdgcn_mfma_f32_32x32x16_f16(al2[mt], bh2[nt], acc2[mt][nt], 0, 0, 0);
                }
        }
        __syncthreads();  // drains prefetch after compute + protects buf reuse
    }

    // epilogue: C/D layout col=lane&31, row=(g&3)+8*(g>>2)+4*q  [m74/m101]
    const float LSC = 4.8828125e-4f;  // 2^-11
    #pragma unroll
    for (int mt = 0; mt < 2; ++mt)
        #pragma unroll
        for (int nt = 0; nt < 2; ++nt) {
            #pragma unroll
            for (int g = 0; g < 16; ++g) {
                int rl = wm * 64 + mt * 32 + (g & 3) + 8 * (g >> 2) + 4 * q;
                int mrow = m0 + rl;
                if (mrow < cnt) {
                    int col = n0 + wn * 64 + nt * 32 + ml;
                    size_t addr = (size_t)(off + mrow) * CD + col;
                    float v = acc1[mt][nt][g] + acc2[mt][nt][g] * LSC;
                    if constexpr (MODE == 0) {
                        BxOut[addr] = v;
                        float z = softt(v, th);
                        _Float16 a, b;
                        fsplit(z, a, b);
                        zh[addr] = a; zl[addr] = b;
                    } else if constexpr (MODE == 1) {
                        float z = softt(v + BxBuf[addr], th);
                        _Float16 a, b;
                        fsplit(z, a, b);
                        zh[addr] = a; zl[addr] = b;
                    } else {
                        zf[addr] = softt(v + BxBuf[addr], th);
                    }
                }
            }
        }
}

// ---------------- K6: per-row top-k threshold, one wave per row, barrier-free.
// Bit search converges to exact kth-largest |z| bits; ballot+popc compaction.
__global__ __launch_bounds__(256)
void k_prune(const float* __restrict__ z, const int* __restrict__ offsets,
             float* __restrict__ cval, int* __restrict__ cidx, int* __restrict__ rcnt) {
    const int SL[KE] = {5, 150, 296, 441, 587, 732, 878, 1024};
    const int t = threadIdx.x;
    const int lane = t & 63;
    const int wv = t >> 6;
    const int slot = blockIdx.x * 4 + wv;
    int k = 0;
    #pragma unroll
    for (int e = 1; e < KE; ++e)
        if (slot >= offsets[e]) k = e;
    const int lvl = SL[k];
    const float* zr = z + (size_t)slot * CD;
    float v[16];
    unsigned ab[16];
    #pragma unroll
    for (int j = 0; j < 16; ++j) {
        v[j] = zr[lane + 64 * j];
        ab[j] = __float_as_uint(fabsf(v[j]));
    }
    unsigned thr = 0;
    for (int b = 30; b >= 0; --b) {
        unsigned cand = thr | (1u << b);
        int c = 0;
        #pragma unroll
        for (int j = 0; j < 16; ++j) c += (ab[j] >= cand) ? 1 : 0;
        #pragma unroll
        for (int off = 1; off < 64; off <<= 1) c += __shfl_xor(c, off, 64);
        if (c >= lvl) thr = cand;
    }
    float* cvr = cval + (size_t)slot * CD;
    int* cir = cidx + (size_t)slot * CD;
    int base = 0;
    #pragma unroll
    for (int j = 0; j < 16; ++j) {
        bool keep = ab[j] >= thr;
        unsigned long long m = __ballot(keep);
        if (keep) {
            int pos = base + __popcll(m & ((1ULL << lane) - 1));
            cvr[pos] = v[j];
            cir[pos] = lane + 64 * j;
        }
        base += __popcll(m);
    }
    if (lane == 0) rcnt[slot] = base;
}

// ---------------- K7: out = relu(h) @ W2 + b2, h = b1 + sparse_z @ W1 (compact lists)
__global__ __launch_bounds__(256)
void k_output(const float* __restrict__ cval, const int* __restrict__ cidx,
              const int* __restrict__ rcnt,
              const float* __restrict__ W1, const float* __restrict__ b1,
              const float* __restrict__ W2, const float* __restrict__ b2,
              const int* __restrict__ perm, float* __restrict__ out) {
    __shared__ float W2s[64][68];
    __shared__ float hTs[64][34];
    __shared__ float cvS[ORB][16];
    __shared__ int   ciS[ORB][16];
    __shared__ int   cnS[ORB];

    const int t = threadIdx.x;
    const int s0 = blockIdx.x * ORB;

    if (t < ORB) cnS[t] = rcnt[s0 + t];
    __syncthreads();
    #pragma unroll
    for (int u = t; u < ORB * 16; u += 256) {
        int r = u >> 4, e = u & 15;
        int cnt = cnS[r];
        cvS[r][e] = (e < cnt) ? cval[(size_t)(s0 + r) * CD + e] : 0.f;
        ciS[r][e] = (e < cnt) ? cidx[(size_t)(s0 + r) * CD + e] : 0;
    }

    const int tm = t >> 4;
    const int tn = t & 15;
    const int iL = t & 63;
    const int rs = t >> 6;

    float acc0[4], acc1[4];
    #pragma unroll
    for (int j = 0; j < 4; ++j) { acc0[j] = 0.f; acc1[j] = 0.f; }

    for (int ch = 0; ch < 16; ++ch) {
        const int i0 = ch * 64;
        __syncthreads();
        #pragma unroll
        for (int p = 0; p < 4; ++p) {
            int kr = (t >> 4) + 16 * p;
            float4 w = *(const float4*)&W2[(size_t)(i0 + kr) * PD + (t & 15) * 4];
            *(float4*)&W2s[kr][(t & 15) * 4] = w;
        }
        float bv = b1[i0 + iL];
        #pragma unroll
        for (int jj = 0; jj < 8; ++jj) {
            int r = rs * 8 + jj;
            int cnt = cnS[r];
            float acc = bv;
            float wv[16];
            #pragma unroll
            for (int e = 0; e < 16; ++e)
                wv[e] = W1[(size_t)ciS[r][e] * CD + i0 + iL];
            #pragma unroll
            for (int e = 0; e < 16; ++e)
                acc = fmaf(cvS[r][e], wv[e], acc);
            if (cnt > 16) {
                const float* cvr = cval + (size_t)(s0 + r) * CD;
                const int* cir = cidx + (size_t)(s0 + r) * CD;
                for (int e = 16; e < cnt; ++e)
                    acc = fmaf(cvr[e], W1[(size_t)cir[e] * CD + i0 + iL], acc);
            }
            hTs[iL][r] = fmaxf(acc, 0.f);
        }
        __syncthreads();
        #pragma unroll 8
        for (int i = 0; i < 64; ++i) {
            float2 h2 = *(const float2*)&hTs[i][2 * tm];
            float4 w4 = *(const float4*)&W2s[i][4 * tn];
            const float* wp = &w4.x;
            #pragma unroll
            for (int j = 0; j < 4; ++j) {
                acc0[j] = fmaf(h2.x, wp[j], acc0[j]);
                acc1[j] = fmaf(h2.y, wp[j], acc1[j]);
            }
        }
    }

    float4 bb = *(const float4*)&b2[4 * tn];
    const float* bp = &bb.x;
    int g0 = perm[s0 + 2 * tm];
    int g1 = perm[s0 + 2 * tm + 1];
    float4 o0, o1;
    #pragma unroll
    for (int j = 0; j < 4; ++j) { (&o0.x)[j] = acc0[j] + bp[j]; (&o1.x)[j] = acc1[j] + bp[j]; }
    *(float4*)&out[(size_t)g0 * PD + 4 * tn] = o0;
    *(float4*)&out[(size_t)g1 * PD + 4 * tn] = o1;
}

extern "C" void kernel_launch(void* const* d_in, const int* in_sizes, int n_in,
                              void* d_out, int out_size, void* d_ws, size_t ws_size,
                              hipStream_t stream) {
    const float* x     = (const float*)d_in[0];
    const float* Wq    = (const float*)d_in[1];
    const float* bq    = (const float*)d_in[2];
    const float* keys  = (const float*)d_in[3];
    const float* We    = (const float*)d_in[4];
    const float* S     = (const float*)d_in[5];
    const float* theta = (const float*)d_in[6];
    const float* W1    = (const float*)d_in[7];
    const float* b1    = (const float*)d_in[8];
    const float* W2    = (const float*)d_in[9];
    const float* b2    = (const float*)d_in[10];
    float* out = (float*)d_out;

    const size_t F = (size_t)NB * CD;  // 8.39M elements
    float* Bx = (float*)d_ws;                         // region 0: F floats
    _Float16* zAh = (_Float16*)(Bx + F);              // region 1: 2F halves
    _Float16* zAl = zAh + F;
    float* R1 = (float*)(zAl + F);                    // region 2: F floats, multi-phase
    _Float16* xh  = (_Float16*)R1;
    _Float16* xl  = xh + (size_t)NB * IND;
    _Float16* weh = xl + (size_t)NB * IND;
    _Float16* wel = weh + (size_t)KE * IND * CD;
    _Float16* zBh = (_Float16*)R1;
    _Float16* zBl = zBh + F;
    float* z1 = R1;
    _Float16* sth = (_Float16*)(R1 + F);              // region 3: 2F halves
    _Float16* stl = sth + F;
    float* M  = (float*)(stl + F);
    float* sb = M + IND * KE;
    int* idx     = (int*)(sb + 8);
    int* perm    = idx + NB;
    int* counts  = perm + NB;
    int* offsets = counts + KE;
    int* rcnt    = offsets + KE;
    float* cval = Bx;
    int*   cidx = (int*)zAh;

    // gating first so tsplit can skip unused experts
    k_precompute_M<<<16, 256, 0, stream>>>(Wq, keys, bq, M, sb);
    k_scores<<<NB / 4, 256, 0, stream>>>(x, M, sb, idx);
    k_count<<<1, 256, 0, stream>>>(idx, perm, counts, offsets);

    k_split_rows<<<(NB * IND) / 1024, 256, 0, stream>>>(x, xh, xl, NB * IND);
    {
        dim3 g(IND / 64, CD / 64, KE);
        k_tsplit<<<g, 256, 0, stream>>>(We, weh, wel, IND, counts);
    }
    {
        dim3 g(CD / 64, CD / 64, KE);
        k_tsplit<<<g, 256, 0, stream>>>(S, sth, stl, CD, counts);
    }

    dim3 gg(CD / 128, NB / 128, KE);
    k_mfma<IND, 0><<<gg, 256, 0, stream>>>(xh, xl, weh, wel, theta, nullptr, Bx, zAh, zAl, nullptr, perm, counts, offsets);
    k_mfma<CD, 1><<<gg, 256, 0, stream>>>(zAh, zAl, sth, stl, theta, Bx, nullptr, zBh, zBl, nullptr, perm, counts, offsets);
    k_mfma<CD, 1><<<gg, 256, 0, stream>>>(zBh, zBl, sth, stl, theta, Bx, nullptr, zAh, zAl, nullptr, perm, counts, offsets);
    k_mfma<CD, 1><<<gg, 256, 0, stream>>>(zAh, zAl, sth, stl, theta, Bx, nullptr, zBh, zBl, nullptr, perm, counts, offsets);
    k_mfma<CD, 1><<<gg, 256, 0, stream>>>(zBh, zBl, sth, stl, theta, Bx, nullptr, zAh, zAl, nullptr, perm, counts, offsets);
    k_mfma<CD, 2><<<gg, 256, 0, stream>>>(zAh, zAl, sth, stl, theta, Bx, nullptr, nullptr, nullptr, z1, perm, counts, offsets);

    k_prune<<<NB / 4, 256, 0, stream>>>(z1, offsets, cval, cidx, rcnt);
    k_output<<<NB / ORB, 256, 0, stream>>>(cval, cidx, rcnt, W1, b1, W2, b2, perm, out);
}